// Round 1
// baseline (608.847 us; speedup 1.0000x reference)
//
#include <hip/hip_runtime.h>
#include <math.h>

#define NQ    6
#define QDIM  64     // 2^6 amplitudes = 1 wave
#define BB    128
#define CC    64
#define TT    2048
#define DD    256
#define NCH   128    // chunks per batch
#define CHLEN 16
#define HH    128    // attention hidden
#define NCP   60     // circuit params per chunk

__device__ __forceinline__ float fast_tanh(float x) {
  float e = __expf(2.f * x);
  return 1.f - 2.f / (e + 1.f);
}

__device__ __forceinline__ float wave_sum(float v) {
#pragma unroll
  for (int off = 32; off >= 1; off >>= 1) v += __shfl_xor(v, off, 64);
  return v;
}

// ---- quantum gates: one statevector per wave, amplitude (re,im) per lane ----
// wire w <-> bit (5-w) of the lane index (wire 0 = MSB).

__device__ __forceinline__ void g_rx(float& re, float& im, int lane, int m, float half) {
  float c = __cosf(half), s = __sinf(half);
  float pre = __shfl_xor(re, m, 64);
  float pim = __shfl_xor(im, m, 64);
  float nre = c * re + s * pim;   // new = c*a - i*s*partner
  float nim = c * im - s * pre;
  re = nre; im = nim;
}

__device__ __forceinline__ void g_ry(float& re, float& im, int lane, int m, float half) {
  float c = __cosf(half), s = __sinf(half);
  float pre = __shfl_xor(re, m, 64);
  float pim = __shfl_xor(im, m, 64);
  float sg = (lane & m) ? s : -s;  // bit0: c*a - s*p ; bit1: c*a + s*p
  re = c * re + sg * pre;
  im = c * im + sg * pim;
}

__device__ __forceinline__ void g_rz(float& re, float& im, int lane, int m, float half) {
  float c = __cosf(half), s = __sinf(half);
  float sg = (lane & m) ? s : -s;  // e^{+-i t/2}
  float nre = c * re - sg * im;
  float nim = c * im + sg * re;
  re = nre; im = nim;
}

__device__ __forceinline__ void g_crx(float& re, float& im, int lane, int mc, int mt, float half) {
  float c = __cosf(half), s = __sinf(half);
  float pre = __shfl_xor(re, mt, 64);   // all lanes shuffle (partner shares ctrl bit)
  float pim = __shfl_xor(im, mt, 64);
  if (lane & mc) {
    float nre = c * re + s * pim;
    float nim = c * im - s * pre;
    re = nre; im = nim;
  }
}

// one ansatz layer = RX,RY,RZ on each qubit, CRX ring forward, CRX ring backward
__device__ __forceinline__ void ansatz_layer(float& re, float& im, int lane,
                                             const float* __restrict__ p) {
#pragma unroll
  for (int q = 0; q < 6; ++q) {
    int m = 1 << (5 - q);
    g_rx(re, im, lane, m, 0.5f * p[3 * q + 0]);
    g_ry(re, im, lane, m, 0.5f * p[3 * q + 1]);
    g_rz(re, im, lane, m, 0.5f * p[3 * q + 2]);
  }
#pragma unroll
  for (int q = 0; q < 6; ++q)
    g_crx(re, im, lane, 1 << (5 - q), 1 << (5 - ((q + 1) % 6)), 0.5f * p[18 + q]);
#pragma unroll
  for (int q = 5; q >= 0; --q)
    g_crx(re, im, lane, 1 << (5 - q), 1 << (5 - ((q + 5) % 6)), 0.5f * p[24 + (5 - q)]);
}

// ============ K1: per-(b,chunk) fused embed + attention + proj ============
__global__ __launch_bounds__(256) void k1_feats_attn_proj(
    const float* __restrict__ x, const float* __restrict__ emb_w,
    const float* __restrict__ emb_b, const float* __restrict__ att_w1,
    const float* __restrict__ att_b1, const float* __restrict__ att_w2,
    const float* __restrict__ proj_w, const float* __restrict__ proj_b,
    float* __restrict__ params_out) {
  const int blk = blockIdx.x;
  const int b = blk >> 7, c = blk & 127;
  const int tid = threadIdx.x;

  __shared__ float xT[64][20];           // x tile, transposed, padded
  __shared__ float featsS[CHLEN][DD];    // 16 x 256
  __shared__ float hS[CHLEN][HH];        // 16 x 128
  __shared__ float scoreS[CHLEN];
  __shared__ float chunkS[DD];

  {  // stage x[b, k, c*16 .. c*16+15] into LDS (64B contiguous per k-row)
    int k = tid >> 2, tq = tid & 3;
    const float4 v = *(const float4*)(x + (((size_t)b * CC + k) * TT + (size_t)c * CHLEN + tq * 4));
    xT[k][tq * 4 + 0] = v.x; xT[k][tq * 4 + 1] = v.y;
    xT[k][tq * 4 + 2] = v.z; xT[k][tq * 4 + 3] = v.w;
  }
  __syncthreads();

  {  // feats[t][d] = sum_k xT[k][t]*emb_w[k][d] + emb_b[d]; thread = 4t x 4d
    const int dq = tid & 63, tq = tid >> 6;
    const int d0 = dq * 4, t0 = tq * 4;
    float acc[4][4];
#pragma unroll
    for (int i = 0; i < 4; ++i)
#pragma unroll
      for (int j = 0; j < 4; ++j) acc[i][j] = 0.f;
    for (int k = 0; k < 64; ++k) {
      float4 xv = *(const float4*)&xT[k][t0];                 // broadcast b128
      float4 wv = *(const float4*)(emb_w + (size_t)k * DD + d0);
      float xa[4] = {xv.x, xv.y, xv.z, xv.w};
      float wa[4] = {wv.x, wv.y, wv.z, wv.w};
#pragma unroll
      for (int ti = 0; ti < 4; ++ti)
#pragma unroll
        for (int dj = 0; dj < 4; ++dj)
          acc[ti][dj] = fmaf(xa[ti], wa[dj], acc[ti][dj]);
    }
    float4 bv = *(const float4*)(emb_b + d0);
    float ba[4] = {bv.x, bv.y, bv.z, bv.w};
#pragma unroll
    for (int ti = 0; ti < 4; ++ti) {
      float4 o;
      o.x = acc[ti][0] + ba[0]; o.y = acc[ti][1] + ba[1];
      o.z = acc[ti][2] + ba[2]; o.w = acc[ti][3] + ba[3];
      *(float4*)&featsS[t0 + ti][d0] = o;
    }
  }
  __syncthreads();

  {  // h[t][j] = tanh(sum_d feats[t][d]*att_w1[d][j] + b1[j]); thread = 4t x 4j, d split 2
    const int jq = tid & 31, tq = (tid >> 5) & 3, dh = tid >> 7;
    const int j0 = jq * 4, t0 = tq * 4;
    float acc[4][4];
#pragma unroll
    for (int i = 0; i < 4; ++i)
#pragma unroll
      for (int j = 0; j < 4; ++j) acc[i][j] = 0.f;
    for (int d4 = 0; d4 < 32; ++d4) {
      int d = (dh * 32 + d4) * 4;
      float fa[4][4];
#pragma unroll
      for (int ti = 0; ti < 4; ++ti) {
        float4 f = *(const float4*)&featsS[t0 + ti][d];
        fa[ti][0] = f.x; fa[ti][1] = f.y; fa[ti][2] = f.z; fa[ti][3] = f.w;
      }
#pragma unroll
      for (int q = 0; q < 4; ++q) {
        float4 w = *(const float4*)(att_w1 + (size_t)(d + q) * HH + j0);
        float wa[4] = {w.x, w.y, w.z, w.w};
#pragma unroll
        for (int ti = 0; ti < 4; ++ti)
#pragma unroll
          for (int jj = 0; jj < 4; ++jj)
            acc[ti][jj] = fmaf(fa[ti][q], wa[jj], acc[ti][jj]);
      }
    }
    if (dh == 0) {
#pragma unroll
      for (int ti = 0; ti < 4; ++ti) {
        float4 o;
        o.x = acc[ti][0]; o.y = acc[ti][1]; o.z = acc[ti][2]; o.w = acc[ti][3];
        *(float4*)&hS[t0 + ti][j0] = o;
      }
    }
    __syncthreads();
    if (dh == 1) {
      float4 bv = *(const float4*)(att_b1 + j0);
      float ba[4] = {bv.x, bv.y, bv.z, bv.w};
#pragma unroll
      for (int ti = 0; ti < 4; ++ti) {
        float4 hv = *(float4*)&hS[t0 + ti][j0];
        float4 o;
        o.x = fast_tanh(hv.x + acc[ti][0] + ba[0]);
        o.y = fast_tanh(hv.y + acc[ti][1] + ba[1]);
        o.z = fast_tanh(hv.z + acc[ti][2] + ba[2]);
        o.w = fast_tanh(hv.w + acc[ti][3] + ba[3]);
        *(float4*)&hS[t0 + ti][j0] = o;
      }
    }
    __syncthreads();
  }

  {  // scores[t] = sum_j h[t][j]*att_w2[j]  (att_b2 dropped: softmax shift-invariant)
    const int wv = tid >> 6, lane = tid & 63;
    float p[4];
#pragma unroll
    for (int ti = 0; ti < 4; ++ti) {
      int t = wv * 4 + ti;
      p[ti] = hS[t][lane] * att_w2[lane] + hS[t][lane + 64] * att_w2[lane + 64];
      p[ti] = wave_sum(p[ti]);
    }
    if (lane == 0) {
#pragma unroll
      for (int ti = 0; ti < 4; ++ti) scoreS[wv * 4 + ti] = p[ti];
    }
    __syncthreads();
  }

  {  // softmax over 16, chunk[d] = sum_t w[t]*feats[t][d], then proj+sigmoid
    float sc[16];
    float mx = -1e30f;
#pragma unroll
    for (int t = 0; t < 16; ++t) { sc[t] = scoreS[t]; mx = fmaxf(mx, sc[t]); }
    float sum = 0.f;
#pragma unroll
    for (int t = 0; t < 16; ++t) { sc[t] = __expf(sc[t] - mx); sum += sc[t]; }
    float inv = 1.f / sum;
    float ch = 0.f;
#pragma unroll
    for (int t = 0; t < 16; ++t) ch = fmaf(sc[t], featsS[t][tid], ch);
    chunkS[tid] = ch * inv;
    __syncthreads();
    if (tid < NCP) {
      float a = proj_b[tid];
      for (int d = 0; d < DD; ++d) a = fmaf(chunkS[d], proj_w[(size_t)d * NCP + tid], a);
      params_out[(size_t)blk * NCP + tid] = 1.f / (1.f + __expf(-a));
    }
  }
}

// ============ K2: 2-layer ansatz, one statevector per wave ============
__global__ __launch_bounds__(256) void k2_ansatz(const float* __restrict__ params,
                                                 float2* __restrict__ evolved) {
  const int gid = blockIdx.x * 256 + threadIdx.x;
  const int gw = gid >> 6, lane = gid & 63;
  const float* p = params + (size_t)gw * NCP;
  float re = (lane == 0) ? 1.f : 0.f, im = 0.f;
  ansatz_layer(re, im, lane, p);
  ansatz_layer(re, im, lane, p + 30);
  evolved[gid] = make_float2(re, im);
}

// ============ K3: LCU mix + qff ansatz + expvals + head ============
__global__ __launch_bounds__(256) void k3_head(
    const float2* __restrict__ evolved, const float* __restrict__ mix_re,
    const float* __restrict__ mix_im, const float* __restrict__ qff,
    const float* __restrict__ out_w, const float* __restrict__ out_b,
    const float* __restrict__ ln_g, const float* __restrict__ ln_b,
    const float* __restrict__ cls_w1, const float* __restrict__ cls_b1,
    const float* __restrict__ cls_w2, const float* __restrict__ cls_b2,
    float* __restrict__ outp) {
  const int b = blockIdx.x, tid = threadIdx.x, wv = tid >> 6, lane = tid & 63;
  __shared__ float mreS[4][64], mimS[4][64];
  __shared__ float qfeatS[18];
  __shared__ float outS[DD];
  __shared__ float redS[4];

  // partial LCU mix over this wave's 32 chunks
  float are = 0.f, aim = 0.f;
  for (int t = wv * 32; t < wv * 32 + 32; ++t) {
    float2 e = evolved[((size_t)b * NCH + t) * QDIM + lane];
    float cr = mix_re[t], ci = mix_im[t];
    are = fmaf(cr, e.x, are); are = fmaf(-ci, e.y, are);
    aim = fmaf(cr, e.y, aim); aim = fmaf(ci, e.x, aim);
  }
  mreS[wv][lane] = are; mimS[wv][lane] = aim;
  __syncthreads();

  if (wv == 0) {
    // S = sum|coeff| + 1e-8 (same for every b)
    float r0 = mix_re[lane], i0 = mix_im[lane];
    float r1 = mix_re[lane + 64], i1 = mix_im[lane + 64];
    float sp = sqrtf(r0 * r0 + i0 * i0) + sqrtf(r1 * r1 + i1 * i1);
    float S = wave_sum(sp) + 1e-8f;
    float re = (mreS[0][lane] + mreS[1][lane]) + (mreS[2][lane] + mreS[3][lane]);
    float im = (mimS[0][lane] + mimS[1][lane]) + (mimS[2][lane] + mimS[3][lane]);
    float invS = 1.f / S;
    re *= invS; im *= invS;
    float n2 = wave_sum(re * re + im * im);
    float scl = 1.f / (sqrtf(n2) + 1e-9f);
    re *= scl; im *= scl;
    // quantum feed-forward: 1 layer, raw (non-sigmoid) shared params
    ansatz_layer(re, im, lane, qff);
    // expvals X_i, Y_i, Z_i
#pragma unroll
    for (int q = 0; q < 6; ++q) {
      int m = 1 << (5 - q);
      float pre = __shfl_xor(re, m, 64), pim = __shfl_xor(im, m, 64);
      float vx = re * pre + im * pim;
      float vy = (lane & m) ? (im * pre - re * pim) : (re * pim - im * pre);
      float vz = (lane & m) ? -(re * re + im * im) : (re * re + im * im);
      vx = wave_sum(vx); vy = wave_sum(vy); vz = wave_sum(vz);
      if (lane == 0) { qfeatS[q] = vx; qfeatS[6 + q] = vy; qfeatS[12 + q] = vz; }
    }
  }
  __syncthreads();

  // out[d] = qfeat @ out_w + out_b
  float o = out_b[tid];
#pragma unroll
  for (int k = 0; k < 18; ++k) o = fmaf(qfeatS[k], out_w[k * DD + tid], o);
  // LayerNorm (biased var)
  float s1 = wave_sum(o);
  if (lane == 0) redS[wv] = s1;
  __syncthreads();
  float mu = (redS[0] + redS[1] + redS[2] + redS[3]) * (1.f / 256.f);
  __syncthreads();
  float dv = o - mu;
  float s2 = wave_sum(dv * dv);
  if (lane == 0) redS[wv] = s2;
  __syncthreads();
  float var = (redS[0] + redS[1] + redS[2] + redS[3]) * (1.f / 256.f);
  __syncthreads();
  float on = dv / sqrtf(var + 1e-5f) * ln_g[tid] + ln_b[tid];
  outS[tid] = on;
  __syncthreads();
  // classifier
  float r = cls_b1[tid];
  for (int d = 0; d < DD; ++d) r = fmaf(outS[d], cls_w1[(size_t)d * DD + tid], r);
  r = fmaxf(r, 0.f);
  float p0 = wave_sum(r * cls_w2[tid * 2 + 0]);
  float p1 = wave_sum(r * cls_w2[tid * 2 + 1]);
  if (lane == 0) redS[wv] = p0;
  __syncthreads();
  float l0 = redS[0] + redS[1] + redS[2] + redS[3];
  __syncthreads();
  if (lane == 0) redS[wv] = p1;
  __syncthreads();
  float l1 = redS[0] + redS[1] + redS[2] + redS[3];
  if (tid == 0) {
    outp[b * 2 + 0] = l0 + cls_b2[0];
    outp[b * 2 + 1] = l1 + cls_b2[1];
  }
}

extern "C" void kernel_launch(void* const* d_in, const int* in_sizes, int n_in,
                              void* d_out, int out_size, void* d_ws, size_t ws_size,
                              hipStream_t stream) {
  const float* x      = (const float*)d_in[0];
  const float* emb_w  = (const float*)d_in[1];
  const float* emb_b  = (const float*)d_in[2];
  const float* att_w1 = (const float*)d_in[3];
  const float* att_b1 = (const float*)d_in[4];
  const float* att_w2 = (const float*)d_in[5];
  // d_in[6] att_b2: unused (softmax is shift-invariant in a per-row constant)
  const float* proj_w = (const float*)d_in[7];
  const float* proj_b = (const float*)d_in[8];
  const float* mix_re = (const float*)d_in[9];
  const float* mix_im = (const float*)d_in[10];
  const float* qff    = (const float*)d_in[11];
  const float* out_w  = (const float*)d_in[12];
  const float* out_b  = (const float*)d_in[13];
  const float* ln_g   = (const float*)d_in[14];
  const float* ln_b   = (const float*)d_in[15];
  const float* cls_w1 = (const float*)d_in[16];
  const float* cls_b1 = (const float*)d_in[17];
  const float* cls_w2 = (const float*)d_in[18];
  const float* cls_b2 = (const float*)d_in[19];

  float*  params  = (float*)d_ws;                                   // 16384*60*4  = 3.93 MB
  float2* evolved = (float2*)((char*)d_ws + (size_t)BB * NCH * NCP * 4);  // +8.39 MB

  k1_feats_attn_proj<<<BB * NCH, 256, 0, stream>>>(
      x, emb_w, emb_b, att_w1, att_b1, att_w2, proj_w, proj_b, params);
  k2_ansatz<<<BB * NCH * QDIM / 256, 256, 0, stream>>>(params, evolved);
  k3_head<<<BB, 256, 0, stream>>>(evolved, mix_re, mix_im, qff, out_w, out_b,
                                  ln_g, ln_b, cls_w1, cls_b1, cls_w2, cls_b2,
                                  (float*)d_out);
}

// Round 2
// 537.682 us; speedup vs baseline: 1.1324x; 1.1324x over previous
//
#include <hip/hip_runtime.h>
#include <math.h>

#define NQ    6
#define QDIM  64     // 2^6 amplitudes = 1 wave
#define BB    128
#define CC    64
#define TT    2048
#define DD    256
#define NCH   128    // chunks per batch
#define CHLEN 16
#define HH    128    // attention hidden
#define NCP   60     // circuit params per chunk

typedef __bf16 bf16x8 __attribute__((ext_vector_type(8)));
typedef float  f32x4  __attribute__((ext_vector_type(4)));

__device__ __forceinline__ float fast_tanh(float x) {
  float e = __expf(2.f * x);
  return 1.f - 2.f / (e + 1.f);
}

__device__ __forceinline__ float wave_sum(float v) {
#pragma unroll
  for (int off = 32; off >= 1; off >>= 1) v += __shfl_xor(v, off, 64);
  return v;
}

// ---- quantum gates: one statevector per wave, amplitude (re,im) per lane ----
// wire w <-> bit (5-w) of the lane index (wire 0 = MSB).

__device__ __forceinline__ void g_rx(float& re, float& im, int lane, int m, float half) {
  float c = __cosf(half), s = __sinf(half);
  float pre = __shfl_xor(re, m, 64);
  float pim = __shfl_xor(im, m, 64);
  float nre = c * re + s * pim;
  float nim = c * im - s * pre;
  re = nre; im = nim;
}

__device__ __forceinline__ void g_ry(float& re, float& im, int lane, int m, float half) {
  float c = __cosf(half), s = __sinf(half);
  float pre = __shfl_xor(re, m, 64);
  float pim = __shfl_xor(im, m, 64);
  float sg = (lane & m) ? s : -s;
  re = c * re + sg * pre;
  im = c * im + sg * pim;
}

__device__ __forceinline__ void g_rz(float& re, float& im, int lane, int m, float half) {
  float c = __cosf(half), s = __sinf(half);
  float sg = (lane & m) ? s : -s;
  float nre = c * re - sg * im;
  float nim = c * im + sg * re;
  re = nre; im = nim;
}

__device__ __forceinline__ void g_crx(float& re, float& im, int lane, int mc, int mt, float half) {
  float c = __cosf(half), s = __sinf(half);
  float pre = __shfl_xor(re, mt, 64);
  float pim = __shfl_xor(im, mt, 64);
  if (lane & mc) {
    float nre = c * re + s * pim;
    float nim = c * im - s * pre;
    re = nre; im = nim;
  }
}

__device__ __forceinline__ void ansatz_layer(float& re, float& im, int lane,
                                             const float* __restrict__ p) {
#pragma unroll
  for (int q = 0; q < 6; ++q) {
    int m = 1 << (5 - q);
    g_rx(re, im, lane, m, 0.5f * p[3 * q + 0]);
    g_ry(re, im, lane, m, 0.5f * p[3 * q + 1]);
    g_rz(re, im, lane, m, 0.5f * p[3 * q + 2]);
  }
#pragma unroll
  for (int q = 0; q < 6; ++q)
    g_crx(re, im, lane, 1 << (5 - q), 1 << (5 - ((q + 1) % 6)), 0.5f * p[18 + q]);
#pragma unroll
  for (int q = 5; q >= 0; --q)
    g_crx(re, im, lane, 1 << (5 - q), 1 << (5 - ((q + 5) % 6)), 0.5f * p[24 + (5 - q)]);
}

// ============ K0: one-time weight prep: split-bf16 + transpose ============
// embT[d][k] (256x64), attT[j][d] (128x256), each as hi/lo bf16 arrays.
__global__ __launch_bounds__(256) void k0_prep(
    const float* __restrict__ emb_w, const float* __restrict__ att_w1,
    __bf16* __restrict__ embH, __bf16* __restrict__ embL,
    __bf16* __restrict__ attH, __bf16* __restrict__ attL) {
  int idx = blockIdx.x * 256 + threadIdx.x;
  if (idx < 64 * 256) {
    int d = idx >> 6, k = idx & 63;
    float v = emb_w[k * 256 + d];
    __bf16 h = (__bf16)v;
    embH[d * 64 + k] = h;
    embL[d * 64 + k] = (__bf16)(v - (float)h);
  }
  int i2 = idx - 64 * 256;
  if (i2 >= 0 && i2 < 128 * 256) {
    int j = i2 >> 8, dd = i2 & 255;
    float v = att_w1[dd * 128 + j];
    __bf16 h = (__bf16)v;
    attH[j * 256 + dd] = h;
    attL[j * 256 + dd] = (__bf16)(v - (float)h);
  }
}

// ============ K1: per-(b,chunk) fused embed(MFMA) + attn(MFMA) + proj ============
// Split-bf16 3-product MFMA: err ~2^-16 rel, fp32-grade.
// MFMA 16x16x32 layouts (m89-verified): A[m=lane&15][k=quad*8+j],
// B[n=lane&15][k=quad*8+j] (from transposed weights), C: col(n)=lane&15, row(m)=quad*4+reg.
__global__ __launch_bounds__(256) void k1_feats_attn_proj(
    const float* __restrict__ x, const float* __restrict__ emb_b,
    const float* __restrict__ att_b1, const float* __restrict__ att_w2,
    const float* __restrict__ proj_w, const float* __restrict__ proj_b,
    const __bf16* __restrict__ embH, const __bf16* __restrict__ embL,
    const __bf16* __restrict__ attH, const __bf16* __restrict__ attL,
    float* __restrict__ params_out) {
  const int blk = blockIdx.x, b = blk >> 7, c = blk & 127;
  const int tid = threadIdx.x, wv = tid >> 6, lane = tid & 63;
  const int l15 = lane & 15, quad = lane >> 4;

  __shared__ float  xtile[16][68];    // x^T tile, stride 68 (272B rows, 16B-aligned)
  __shared__ __bf16 fH[16][272];      // feats hi (544B rows)
  __shared__ __bf16 fL[16][272];      // feats lo
  __shared__ float  hS[16][132];
  __shared__ float  scoreS[16];
  __shared__ float  chunkS[256];
  __shared__ float  projR[4][64];

  {  // stage x[b, k, c*16+t] -> xtile[t][k] (coalesced 16B global loads)
    int k = tid >> 2, tq = tid & 3;
    float4 v = *(const float4*)(x + ((size_t)(b * 64 + k)) * 2048 + c * 16 + tq * 4);
    xtile[tq * 4 + 0][k] = v.x; xtile[tq * 4 + 1][k] = v.y;
    xtile[tq * 4 + 2][k] = v.z; xtile[tq * 4 + 3][k] = v.w;
  }
  __syncthreads();

  // A1 fragments: feats GEMM, M=16(t) K=64(k), 2 k-steps
  bf16x8 a1h[2], a1l[2];
#pragma unroll
  for (int s = 0; s < 2; ++s) {
    const float* src = &xtile[l15][32 * s + 8 * quad];
    float4 u0 = *(const float4*)src;
    float4 u1 = *(const float4*)(src + 4);
    float vals[8] = {u0.x, u0.y, u0.z, u0.w, u1.x, u1.y, u1.z, u1.w};
#pragma unroll
    for (int j = 0; j < 8; ++j) {
      __bf16 h = (__bf16)vals[j];
      a1h[s][j] = h;
      a1l[s][j] = (__bf16)(vals[j] - (float)h);
    }
  }

  {  // GEMM1: feats[16][256] = x^T @ emb_w ; wave owns d = wv*64 .. +63 (4 tiles)
    f32x4 acc[4] = {{0.f,0.f,0.f,0.f},{0.f,0.f,0.f,0.f},{0.f,0.f,0.f,0.f},{0.f,0.f,0.f,0.f}};
#pragma unroll
    for (int ti = 0; ti < 4; ++ti) {
      const size_t row = (size_t)(wv * 64 + ti * 16 + l15) * 64 + 8 * quad;
#pragma unroll
      for (int s = 0; s < 2; ++s) {
        bf16x8 bh = *(const bf16x8*)(embH + row + 32 * s);
        bf16x8 bl = *(const bf16x8*)(embL + row + 32 * s);
        acc[ti] = __builtin_amdgcn_mfma_f32_16x16x32_bf16(a1h[s], bh, acc[ti], 0, 0, 0);
        acc[ti] = __builtin_amdgcn_mfma_f32_16x16x32_bf16(a1l[s], bh, acc[ti], 0, 0, 0);
        acc[ti] = __builtin_amdgcn_mfma_f32_16x16x32_bf16(a1h[s], bl, acc[ti], 0, 0, 0);
      }
    }
    // epilogue: +bias, split to bf16 hi/lo in LDS
#pragma unroll
    for (int ti = 0; ti < 4; ++ti) {
      int d = wv * 64 + ti * 16 + l15;
      float bias = emb_b[d];
#pragma unroll
      for (int r = 0; r < 4; ++r) {
        int t = quad * 4 + r;
        float v = acc[ti][r] + bias;
        __bf16 h = (__bf16)v;
        fH[t][d] = h;
        fL[t][d] = (__bf16)(v - (float)h);
      }
    }
  }
  __syncthreads();

  {  // GEMM2: h[16][128] = tanh(feats @ att_w1 + b1); wave owns j = wv*32 .. +31
    f32x4 acc2[2] = {{0.f,0.f,0.f,0.f},{0.f,0.f,0.f,0.f}};
    const int j0 = wv * 32;
#pragma unroll
    for (int s = 0; s < 8; ++s) {
      bf16x8 ah = *(const bf16x8*)&fH[l15][32 * s + 8 * quad];
      bf16x8 al = *(const bf16x8*)&fL[l15][32 * s + 8 * quad];
#pragma unroll
      for (int jt = 0; jt < 2; ++jt) {
        const size_t row = (size_t)(j0 + jt * 16 + l15) * 256 + 32 * s + 8 * quad;
        bf16x8 bh = *(const bf16x8*)(attH + row);
        bf16x8 bl = *(const bf16x8*)(attL + row);
        acc2[jt] = __builtin_amdgcn_mfma_f32_16x16x32_bf16(ah, bh, acc2[jt], 0, 0, 0);
        acc2[jt] = __builtin_amdgcn_mfma_f32_16x16x32_bf16(al, bh, acc2[jt], 0, 0, 0);
        acc2[jt] = __builtin_amdgcn_mfma_f32_16x16x32_bf16(ah, bl, acc2[jt], 0, 0, 0);
      }
    }
#pragma unroll
    for (int jt = 0; jt < 2; ++jt) {
      int j = j0 + jt * 16 + l15;
      float bias = att_b1[j];
#pragma unroll
      for (int r = 0; r < 4; ++r) {
        int t = quad * 4 + r;
        hS[t][j] = fast_tanh(acc2[jt][r] + bias);
      }
    }
  }
  __syncthreads();

  {  // scores[t] = h[t] . att_w2  (att_b2 dropped: softmax shift-invariant)
    float p[4];
#pragma unroll
    for (int ti = 0; ti < 4; ++ti) {
      int t = wv * 4 + ti;
      p[ti] = wave_sum(hS[t][lane] * att_w2[lane] + hS[t][lane + 64] * att_w2[lane + 64]);
    }
    if (lane == 0) {
#pragma unroll
      for (int ti = 0; ti < 4; ++ti) scoreS[wv * 4 + ti] = p[ti];
    }
  }
  __syncthreads();

  {  // softmax over 16, chunk[d] = sum_t w[t]*feats[t][d] (hi+lo reconstruct)
    float sc[16];
    float mx = -1e30f;
#pragma unroll
    for (int t = 0; t < 16; ++t) { sc[t] = scoreS[t]; mx = fmaxf(mx, sc[t]); }
    float sum = 0.f;
#pragma unroll
    for (int t = 0; t < 16; ++t) { sc[t] = __expf(sc[t] - mx); sum += sc[t]; }
    float inv = 1.f / sum;
    float ch = 0.f;
#pragma unroll
    for (int t = 0; t < 16; ++t) {
      float f = (float)fH[t][tid] + (float)fL[t][tid];
      ch = fmaf(sc[t], f, ch);
    }
    chunkS[tid] = ch * inv;
  }
  __syncthreads();

  // proj: 240 threads = 60 outputs x 4 d-slices, then reduce
  if (tid < 240) {
    int j = tid % 60, sl = tid / 60;
    const float* cs = &chunkS[sl * 64];
    const float* pw = proj_w + (size_t)(sl * 64) * 60 + j;
    float a = 0.f;
#pragma unroll 8
    for (int d = 0; d < 64; ++d) a = fmaf(cs[d], pw[(size_t)d * 60], a);
    projR[sl][j] = a;
  }
  __syncthreads();
  if (tid < 60) {
    float a = proj_b[tid] + (projR[0][tid] + projR[1][tid]) + (projR[2][tid] + projR[3][tid]);
    params_out[(size_t)blk * 60 + tid] = 1.f / (1.f + __expf(-a));
  }
}

// ============ K2: 2-layer ansatz, one statevector per wave ============
__global__ __launch_bounds__(256) void k2_ansatz(const float* __restrict__ params,
                                                 float2* __restrict__ evolved) {
  const int gid = blockIdx.x * 256 + threadIdx.x;
  const int gw = gid >> 6, lane = gid & 63;
  const float* p = params + (size_t)gw * NCP;
  float re = (lane == 0) ? 1.f : 0.f, im = 0.f;
  ansatz_layer(re, im, lane, p);
  ansatz_layer(re, im, lane, p + 30);
  evolved[gid] = make_float2(re, im);
}

// ============ K3: LCU mix + qff ansatz + expvals + head ============
__global__ __launch_bounds__(256) void k3_head(
    const float2* __restrict__ evolved, const float* __restrict__ mix_re,
    const float* __restrict__ mix_im, const float* __restrict__ qff,
    const float* __restrict__ out_w, const float* __restrict__ out_b,
    const float* __restrict__ ln_g, const float* __restrict__ ln_b,
    const float* __restrict__ cls_w1, const float* __restrict__ cls_b1,
    const float* __restrict__ cls_w2, const float* __restrict__ cls_b2,
    float* __restrict__ outp) {
  const int b = blockIdx.x, tid = threadIdx.x, wv = tid >> 6, lane = tid & 63;
  __shared__ float mreS[4][64], mimS[4][64];
  __shared__ float qfeatS[18];
  __shared__ float outS[DD];
  __shared__ float redS[4];

  float are = 0.f, aim = 0.f;
  for (int t = wv * 32; t < wv * 32 + 32; ++t) {
    float2 e = evolved[((size_t)b * NCH + t) * QDIM + lane];
    float cr = mix_re[t], ci = mix_im[t];
    are = fmaf(cr, e.x, are); are = fmaf(-ci, e.y, are);
    aim = fmaf(cr, e.y, aim); aim = fmaf(ci, e.x, aim);
  }
  mreS[wv][lane] = are; mimS[wv][lane] = aim;
  __syncthreads();

  if (wv == 0) {
    float r0 = mix_re[lane], i0 = mix_im[lane];
    float r1 = mix_re[lane + 64], i1 = mix_im[lane + 64];
    float sp = sqrtf(r0 * r0 + i0 * i0) + sqrtf(r1 * r1 + i1 * i1);
    float S = wave_sum(sp) + 1e-8f;
    float re = (mreS[0][lane] + mreS[1][lane]) + (mreS[2][lane] + mreS[3][lane]);
    float im = (mimS[0][lane] + mimS[1][lane]) + (mimS[2][lane] + mimS[3][lane]);
    float invS = 1.f / S;
    re *= invS; im *= invS;
    float n2 = wave_sum(re * re + im * im);
    float scl = 1.f / (sqrtf(n2) + 1e-9f);
    re *= scl; im *= scl;
    ansatz_layer(re, im, lane, qff);
#pragma unroll
    for (int q = 0; q < 6; ++q) {
      int m = 1 << (5 - q);
      float pre = __shfl_xor(re, m, 64), pim = __shfl_xor(im, m, 64);
      float vx = re * pre + im * pim;
      float vy = (lane & m) ? (im * pre - re * pim) : (re * pim - im * pre);
      float vz = (lane & m) ? -(re * re + im * im) : (re * re + im * im);
      vx = wave_sum(vx); vy = wave_sum(vy); vz = wave_sum(vz);
      if (lane == 0) { qfeatS[q] = vx; qfeatS[6 + q] = vy; qfeatS[12 + q] = vz; }
    }
  }
  __syncthreads();

  float o = out_b[tid];
#pragma unroll
  for (int k = 0; k < 18; ++k) o = fmaf(qfeatS[k], out_w[k * DD + tid], o);
  float s1 = wave_sum(o);
  if (lane == 0) redS[wv] = s1;
  __syncthreads();
  float mu = (redS[0] + redS[1] + redS[2] + redS[3]) * (1.f / 256.f);
  __syncthreads();
  float dv = o - mu;
  float s2 = wave_sum(dv * dv);
  if (lane == 0) redS[wv] = s2;
  __syncthreads();
  float var = (redS[0] + redS[1] + redS[2] + redS[3]) * (1.f / 256.f);
  __syncthreads();
  float on = dv / sqrtf(var + 1e-5f) * ln_g[tid] + ln_b[tid];
  outS[tid] = on;
  __syncthreads();
  float r = cls_b1[tid];
  for (int d = 0; d < DD; ++d) r = fmaf(outS[d], cls_w1[(size_t)d * DD + tid], r);
  r = fmaxf(r, 0.f);
  float p0 = wave_sum(r * cls_w2[tid * 2 + 0]);
  float p1 = wave_sum(r * cls_w2[tid * 2 + 1]);
  if (lane == 0) redS[wv] = p0;
  __syncthreads();
  float l0 = redS[0] + redS[1] + redS[2] + redS[3];
  __syncthreads();
  if (lane == 0) redS[wv] = p1;
  __syncthreads();
  float l1 = redS[0] + redS[1] + redS[2] + redS[3];
  if (tid == 0) {
    outp[b * 2 + 0] = l0 + cls_b2[0];
    outp[b * 2 + 1] = l1 + cls_b2[1];
  }
}

extern "C" void kernel_launch(void* const* d_in, const int* in_sizes, int n_in,
                              void* d_out, int out_size, void* d_ws, size_t ws_size,
                              hipStream_t stream) {
  const float* x      = (const float*)d_in[0];
  const float* emb_w  = (const float*)d_in[1];
  const float* emb_b  = (const float*)d_in[2];
  const float* att_w1 = (const float*)d_in[3];
  const float* att_b1 = (const float*)d_in[4];
  const float* att_w2 = (const float*)d_in[5];
  // d_in[6] att_b2: unused (softmax shift-invariant)
  const float* proj_w = (const float*)d_in[7];
  const float* proj_b = (const float*)d_in[8];
  const float* mix_re = (const float*)d_in[9];
  const float* mix_im = (const float*)d_in[10];
  const float* qff    = (const float*)d_in[11];
  const float* out_w  = (const float*)d_in[12];
  const float* out_b  = (const float*)d_in[13];
  const float* ln_g   = (const float*)d_in[14];
  const float* ln_b   = (const float*)d_in[15];
  const float* cls_w1 = (const float*)d_in[16];
  const float* cls_b1 = (const float*)d_in[17];
  const float* cls_w2 = (const float*)d_in[18];
  const float* cls_b2 = (const float*)d_in[19];

  char* ws = (char*)d_ws;
  float*  params  = (float*)ws;                               // 16384*60*4  = 3,932,160
  float2* evolved = (float2*)(ws + 3932160);                  // 16384*64*8  = 8,388,608
  __bf16* embH = (__bf16*)(ws + 12320768);                    // 256*64*2 = 32,768
  __bf16* embL = (__bf16*)(ws + 12320768 + 32768);
  __bf16* attH = (__bf16*)(ws + 12320768 + 2 * 32768);        // 128*256*2 = 65,536
  __bf16* attL = (__bf16*)(ws + 12320768 + 2 * 32768 + 65536);  // end ~12.52 MB

  k0_prep<<<192, 256, 0, stream>>>(emb_w, att_w1, embH, embL, attH, attL);
  k1_feats_attn_proj<<<BB * NCH, 256, 0, stream>>>(
      x, emb_b, att_b1, att_w2, proj_w, proj_b, embH, embL, attH, attL, params);
  k2_ansatz<<<BB * NCH * QDIM / 256, 256, 0, stream>>>(params, evolved);
  k3_head<<<BB, 256, 0, stream>>>(evolved, mix_re, mix_im, qff, out_w, out_b,
                                  ln_g, ln_b, cls_w1, cls_b1, cls_w2, cls_b2,
                                  (float*)d_out);
}

// Round 3
// 400.131 us; speedup vs baseline: 1.5216x; 1.3438x over previous
//
#include <hip/hip_runtime.h>
#include <math.h>

#define NQ    6
#define QDIM  64
#define BB    128
#define CC    64
#define TT    2048
#define DD    256
#define NCH   128
#define CHLEN 16
#define HH    128
#define NCP   60

typedef __bf16 bf16x8 __attribute__((ext_vector_type(8)));
typedef float  f32x4  __attribute__((ext_vector_type(4)));

__device__ __forceinline__ float fast_tanh(float x) {
  float e = __expf(2.f * x);
  return 1.f - 2.f / (e + 1.f);
}

__device__ __forceinline__ float wave_sum(float v) {
#pragma unroll
  for (int off = 32; off >= 1; off >>= 1) v += __shfl_xor(v, off, 64);
  return v;
}

// ---- quantum gates: one statevector per wave, (re,im) per lane ----
__device__ __forceinline__ void g_rx(float& re, float& im, int lane, int m, float half) {
  float c = __cosf(half), s = __sinf(half);
  float pre = __shfl_xor(re, m, 64);
  float pim = __shfl_xor(im, m, 64);
  float nre = c * re + s * pim;
  float nim = c * im - s * pre;
  re = nre; im = nim;
}
__device__ __forceinline__ void g_ry(float& re, float& im, int lane, int m, float half) {
  float c = __cosf(half), s = __sinf(half);
  float pre = __shfl_xor(re, m, 64);
  float pim = __shfl_xor(im, m, 64);
  float sg = (lane & m) ? s : -s;
  re = c * re + sg * pre;
  im = c * im + sg * pim;
}
__device__ __forceinline__ void g_rz(float& re, float& im, int lane, int m, float half) {
  float c = __cosf(half), s = __sinf(half);
  float sg = (lane & m) ? s : -s;
  float nre = c * re - sg * im;
  float nim = c * im + sg * re;
  re = nre; im = nim;
}
__device__ __forceinline__ void g_crx(float& re, float& im, int lane, int mc, int mt, float half) {
  float c = __cosf(half), s = __sinf(half);
  float pre = __shfl_xor(re, mt, 64);
  float pim = __shfl_xor(im, mt, 64);
  if (lane & mc) {
    float nre = c * re + s * pim;
    float nim = c * im - s * pre;
    re = nre; im = nim;
  }
}
__device__ __forceinline__ void ansatz_layer(float& re, float& im, int lane,
                                             const float* p) {
#pragma unroll
  for (int q = 0; q < 6; ++q) {
    int m = 1 << (5 - q);
    g_rx(re, im, lane, m, 0.5f * p[3 * q + 0]);
    g_ry(re, im, lane, m, 0.5f * p[3 * q + 1]);
    g_rz(re, im, lane, m, 0.5f * p[3 * q + 2]);
  }
#pragma unroll
  for (int q = 0; q < 6; ++q)
    g_crx(re, im, lane, 1 << (5 - q), 1 << (5 - ((q + 1) % 6)), 0.5f * p[18 + q]);
#pragma unroll
  for (int q = 5; q >= 0; --q)
    g_crx(re, im, lane, 1 << (5 - q), 1 << (5 - ((q + 5) % 6)), 0.5f * p[24 + (5 - q)]);
}

// ============ K0: one-time weight prep: split-bf16 + transpose ============
// embT[d][k] 256x64, attT[j][d] 128x256, projT[n][d] 64x256 (rows>=60 zero)
__global__ __launch_bounds__(256) void k0_prep(
    const float* __restrict__ emb_w, const float* __restrict__ att_w1,
    const float* __restrict__ proj_w,
    __bf16* __restrict__ embH, __bf16* __restrict__ embL,
    __bf16* __restrict__ attH, __bf16* __restrict__ attL,
    __bf16* __restrict__ projTH, __bf16* __restrict__ projTL) {
  int idx = blockIdx.x * 256 + threadIdx.x;
  if (idx < 16384) {                       // emb: 256d x 64k
    int d = idx >> 6, k = idx & 63;
    float v = emb_w[k * 256 + d];
    __bf16 h = (__bf16)v;
    embH[idx] = h; embL[idx] = (__bf16)(v - (float)h);
  } else if (idx < 49152) {                // att: 128j x 256d
    int i = idx - 16384;
    int j = i >> 8, d = i & 255;
    float v = att_w1[d * 128 + j];
    __bf16 h = (__bf16)v;
    attH[i] = h; attL[i] = (__bf16)(v - (float)h);
  } else {                                 // projT: 64n x 256d
    int i = idx - 49152;
    int n = i >> 8, d = i & 255;
    float v = (n < 60) ? proj_w[d * 60 + n] : 0.f;
    __bf16 h = (__bf16)v;
    projTH[i] = h; projTL[i] = (__bf16)(v - (float)h);
  }
}

// ============ K1: 2 chunks/block, fused embed+attn+softmax+agg+proj ============
// Split-bf16 3-product MFMA (err ~2^-16). m89 layouts: A[m=lane&15][k=quad*8+j],
// B[n=lane&15][k=quad*8+j] (transposed weights), C: n=lane&15, m=quad*4+reg.
__global__ __launch_bounds__(256, 3) void k1_feats_attn_proj(
    const float* __restrict__ x, const float* __restrict__ emb_b,
    const float* __restrict__ att_b1, const float* __restrict__ att_w2,
    const float* __restrict__ proj_b,
    const __bf16* __restrict__ embH, const __bf16* __restrict__ embL,
    const __bf16* __restrict__ attH, const __bf16* __restrict__ attL,
    const __bf16* __restrict__ projTH, const __bf16* __restrict__ projTL,
    float* __restrict__ params_out) {
  const int blk = blockIdx.x;            // 8192 = 128 b x 64 chunk-pairs
  const int b = blk >> 6, cp = blk & 63;
  const int tid = threadIdx.x, wv = tid >> 6, lane = tid & 63;
  const int l15 = lane & 15, quad = lane >> 4;

  __shared__ float  xtile[32][68];       // x^T [t][k], word-stride 68 (2-way free)
  __shared__ __bf16 fH[32][264];         // feats hi, word-stride 132 (2-way free)
  __shared__ __bf16 fL[32][264];
  __shared__ float  scoreP[4][32];
  __shared__ float  wSm[2][16];
  __shared__ float  chunkS[2][256];

  {  // stage x[b, k, cp*32 + t] -> xtile[t][k], 2 passes, coalesced 16B loads
#pragma unroll
    for (int pass = 0; pass < 2; ++pass) {
      int k = pass * 32 + (tid >> 3), t4 = tid & 7;
      float4 v = *(const float4*)(x + ((size_t)(b * 64 + k)) * 2048 + cp * 32 + t4 * 4);
      xtile[t4 * 4 + 0][k] = v.x; xtile[t4 * 4 + 1][k] = v.y;
      xtile[t4 * 4 + 2][k] = v.z; xtile[t4 * 4 + 3][k] = v.w;
    }
  }
  __syncthreads();

  {  // GEMM1: feats[32][256] = x^T @ emb_w; wave owns d = wv*64..+63
    bf16x8 ah[2][2], al[2][2];           // [mt][s]
#pragma unroll
    for (int mt = 0; mt < 2; ++mt)
#pragma unroll
      for (int s = 0; s < 2; ++s) {
        const float* src = &xtile[mt * 16 + l15][32 * s + 8 * quad];
        float4 u0 = *(const float4*)src, u1 = *(const float4*)(src + 4);
        float vals[8] = {u0.x, u0.y, u0.z, u0.w, u1.x, u1.y, u1.z, u1.w};
#pragma unroll
        for (int j = 0; j < 8; ++j) {
          __bf16 h = (__bf16)vals[j];
          ah[mt][s][j] = h;
          al[mt][s][j] = (__bf16)(vals[j] - (float)h);
        }
      }
    f32x4 acc[4][2];                     // [nt][mt]
#pragma unroll
    for (int nt = 0; nt < 4; ++nt)
#pragma unroll
      for (int mt = 0; mt < 2; ++mt) acc[nt][mt] = (f32x4){0.f, 0.f, 0.f, 0.f};
#pragma unroll
    for (int nt = 0; nt < 4; ++nt) {
      const size_t row = (size_t)(wv * 64 + nt * 16 + l15) * 64 + 8 * quad;
      bf16x8 bh0 = *(const bf16x8*)(embH + row);
      bf16x8 bl0 = *(const bf16x8*)(embL + row);
      bf16x8 bh1 = *(const bf16x8*)(embH + row + 32);
      bf16x8 bl1 = *(const bf16x8*)(embL + row + 32);
#pragma unroll
      for (int mt = 0; mt < 2; ++mt) {
        acc[nt][mt] = __builtin_amdgcn_mfma_f32_16x16x32_bf16(ah[mt][0], bh0, acc[nt][mt], 0, 0, 0);
        acc[nt][mt] = __builtin_amdgcn_mfma_f32_16x16x32_bf16(al[mt][0], bh0, acc[nt][mt], 0, 0, 0);
        acc[nt][mt] = __builtin_amdgcn_mfma_f32_16x16x32_bf16(ah[mt][0], bl0, acc[nt][mt], 0, 0, 0);
        acc[nt][mt] = __builtin_amdgcn_mfma_f32_16x16x32_bf16(ah[mt][1], bh1, acc[nt][mt], 0, 0, 0);
        acc[nt][mt] = __builtin_amdgcn_mfma_f32_16x16x32_bf16(al[mt][1], bh1, acc[nt][mt], 0, 0, 0);
        acc[nt][mt] = __builtin_amdgcn_mfma_f32_16x16x32_bf16(ah[mt][1], bl1, acc[nt][mt], 0, 0, 0);
      }
    }
    // epilogue: +bias, split hi/lo into LDS
#pragma unroll
    for (int nt = 0; nt < 4; ++nt) {
      int d = wv * 64 + nt * 16 + l15;
      float bias = emb_b[d];
#pragma unroll
      for (int mt = 0; mt < 2; ++mt)
#pragma unroll
        for (int r = 0; r < 4; ++r) {
          int t = mt * 16 + quad * 4 + r;
          float v = acc[nt][mt][r] + bias;
          __bf16 h = (__bf16)v;
          fH[t][d] = h;
          fL[t][d] = (__bf16)(v - (float)h);
        }
    }
  }
  __syncthreads();

  {  // GEMM2: h = tanh(feats @ att_w1 + b1), fused scores = h . att_w2
    f32x4 acc2[2][2];                    // [mt][jt]
#pragma unroll
    for (int mt = 0; mt < 2; ++mt)
#pragma unroll
      for (int jt = 0; jt < 2; ++jt) acc2[mt][jt] = (f32x4){0.f, 0.f, 0.f, 0.f};
#pragma unroll
    for (int s = 0; s < 8; ++s) {
      bf16x8 fa[2], fb[2];
#pragma unroll
      for (int mt = 0; mt < 2; ++mt) {
        fa[mt] = *(const bf16x8*)&fH[mt * 16 + l15][32 * s + 8 * quad];
        fb[mt] = *(const bf16x8*)&fL[mt * 16 + l15][32 * s + 8 * quad];
      }
#pragma unroll
      for (int jt = 0; jt < 2; ++jt) {
        const size_t row = (size_t)(wv * 32 + jt * 16 + l15) * 256 + 32 * s + 8 * quad;
        bf16x8 bh = *(const bf16x8*)(attH + row);
        bf16x8 bl = *(const bf16x8*)(attL + row);
#pragma unroll
        for (int mt = 0; mt < 2; ++mt) {
          acc2[mt][jt] = __builtin_amdgcn_mfma_f32_16x16x32_bf16(fa[mt], bh, acc2[mt][jt], 0, 0, 0);
          acc2[mt][jt] = __builtin_amdgcn_mfma_f32_16x16x32_bf16(fb[mt], bh, acc2[mt][jt], 0, 0, 0);
          acc2[mt][jt] = __builtin_amdgcn_mfma_f32_16x16x32_bf16(fa[mt], bl, acc2[mt][jt], 0, 0, 0);
        }
      }
    }
    // epilogue: tanh, * w2[j], reduce over the 16 j's in l15, stash per-wave partial
    float w2v[2], b1v[2];
#pragma unroll
    for (int jt = 0; jt < 2; ++jt) {
      int j = wv * 32 + jt * 16 + l15;
      w2v[jt] = att_w2[j];
      b1v[jt] = att_b1[j];
    }
#pragma unroll
    for (int mt = 0; mt < 2; ++mt)
#pragma unroll
      for (int r = 0; r < 4; ++r) {
        float sc = fast_tanh(acc2[mt][0][r] + b1v[0]) * w2v[0] +
                   fast_tanh(acc2[mt][1][r] + b1v[1]) * w2v[1];
        sc += __shfl_xor(sc, 1, 64);
        sc += __shfl_xor(sc, 2, 64);
        sc += __shfl_xor(sc, 4, 64);
        sc += __shfl_xor(sc, 8, 64);
        if (l15 == 0) scoreP[wv][mt * 16 + quad * 4 + r] = sc;
      }
  }
  __syncthreads();

  if (tid < 2) {  // softmax over 16 per chunk (att_b2 dropped: shift-invariant)
    float s[16], mx = -1e30f;
#pragma unroll
    for (int t = 0; t < 16; ++t) {
      int tt = tid * 16 + t;
      s[t] = (scoreP[0][tt] + scoreP[1][tt]) + (scoreP[2][tt] + scoreP[3][tt]);
      mx = fmaxf(mx, s[t]);
    }
    float sum = 0.f;
#pragma unroll
    for (int t = 0; t < 16; ++t) { s[t] = __expf(s[t] - mx); sum += s[t]; }
    float inv = 1.f / sum;
#pragma unroll
    for (int t = 0; t < 16; ++t) wSm[tid][t] = s[t] * inv;
  }
  __syncthreads();

  {  // chunk[c][d] = sum_t w[c,t] * feats[c*16+t][d]
    int d = tid;
#pragma unroll
    for (int c = 0; c < 2; ++c) {
      float a = 0.f;
#pragma unroll
      for (int t = 0; t < 16; ++t) {
        float f = (float)fH[c * 16 + t][d] + (float)fL[c * 16 + t][d];
        a = fmaf(wSm[c][t], f, a);
      }
      chunkS[c][d] = a;
    }
  }
  __syncthreads();

  {  // proj via MFMA: params[2][60] = sigmoid(chunk @ proj_w + b); A rows>=2 zero
    f32x4 acc3 = (f32x4){0.f, 0.f, 0.f, 0.f};
#pragma unroll
    for (int s = 0; s < 8; ++s) {
      bf16x8 ah = (bf16x8)(__bf16)0.f, al = (bf16x8)(__bf16)0.f;
      if (l15 < 2) {
        const float* cs = &chunkS[l15][32 * s + 8 * quad];
        float4 u0 = *(const float4*)cs, u1 = *(const float4*)(cs + 4);
        float vals[8] = {u0.x, u0.y, u0.z, u0.w, u1.x, u1.y, u1.z, u1.w};
#pragma unroll
        for (int j = 0; j < 8; ++j) {
          __bf16 h = (__bf16)vals[j];
          ah[j] = h;
          al[j] = (__bf16)(vals[j] - (float)h);
        }
      }
      const size_t row = (size_t)(wv * 16 + l15) * 256 + 32 * s + 8 * quad;
      bf16x8 bh = *(const bf16x8*)(projTH + row);
      bf16x8 bl = *(const bf16x8*)(projTL + row);
      acc3 = __builtin_amdgcn_mfma_f32_16x16x32_bf16(ah, bh, acc3, 0, 0, 0);
      acc3 = __builtin_amdgcn_mfma_f32_16x16x32_bf16(al, bh, acc3, 0, 0, 0);
      acc3 = __builtin_amdgcn_mfma_f32_16x16x32_bf16(ah, bl, acc3, 0, 0, 0);
    }
    int jout = wv * 16 + l15;
    if (jout < 60 && quad == 0) {
#pragma unroll
      for (int r = 0; r < 2; ++r) {  // c = quad*4 + r, valid c < 2
        float a = acc3[r] + proj_b[jout];
        params_out[((size_t)blk * 2 + r) * 60 + jout] = 1.f / (1.f + __expf(-a));
      }
    }
  }
}

// ============ K2: 2-layer ansatz, one statevector per wave ============
__global__ __launch_bounds__(256) void k2_ansatz(const float* __restrict__ params,
                                                 float2* __restrict__ evolved) {
  const int gid = blockIdx.x * 256 + threadIdx.x;
  const int gw = gid >> 6, lane = gid & 63;
  // preload all 60 params as float4 (kills dependent-load chain)
  const float4* p4 = (const float4*)(params + (size_t)gw * NCP);
  float p[60];
#pragma unroll
  for (int i = 0; i < 15; ++i) {
    float4 v = p4[i];
    p[4 * i + 0] = v.x; p[4 * i + 1] = v.y; p[4 * i + 2] = v.z; p[4 * i + 3] = v.w;
  }
  float re = (lane == 0) ? 1.f : 0.f, im = 0.f;
  ansatz_layer(re, im, lane, p);
  ansatz_layer(re, im, lane, p + 30);
  evolved[gid] = make_float2(re, im);
}

// ============ K3: LCU mix + qff ansatz + expvals + head ============
__global__ __launch_bounds__(256) void k3_head(
    const float2* __restrict__ evolved, const float* __restrict__ mix_re,
    const float* __restrict__ mix_im, const float* __restrict__ qff,
    const float* __restrict__ out_w, const float* __restrict__ out_b,
    const float* __restrict__ ln_g, const float* __restrict__ ln_b,
    const float* __restrict__ cls_w1, const float* __restrict__ cls_b1,
    const float* __restrict__ cls_w2, const float* __restrict__ cls_b2,
    float* __restrict__ outp) {
  const int b = blockIdx.x, tid = threadIdx.x, wv = tid >> 6, lane = tid & 63;
  __shared__ float mreS[4][64], mimS[4][64];
  __shared__ float qfeatS[18];
  __shared__ float outS[DD];
  __shared__ float redS[4];

  float are = 0.f, aim = 0.f;
#pragma unroll 4
  for (int t = wv * 32; t < wv * 32 + 32; ++t) {
    float2 e = evolved[((size_t)b * NCH + t) * QDIM + lane];
    float cr = mix_re[t], ci = mix_im[t];
    are = fmaf(cr, e.x, are); are = fmaf(-ci, e.y, are);
    aim = fmaf(cr, e.y, aim); aim = fmaf(ci, e.x, aim);
  }
  mreS[wv][lane] = are; mimS[wv][lane] = aim;
  __syncthreads();

  if (wv == 0) {
    float r0 = mix_re[lane], i0 = mix_im[lane];
    float r1 = mix_re[lane + 64], i1 = mix_im[lane + 64];
    float sp = sqrtf(r0 * r0 + i0 * i0) + sqrtf(r1 * r1 + i1 * i1);
    float S = wave_sum(sp) + 1e-8f;
    float re = (mreS[0][lane] + mreS[1][lane]) + (mreS[2][lane] + mreS[3][lane]);
    float im = (mimS[0][lane] + mimS[1][lane]) + (mimS[2][lane] + mimS[3][lane]);
    float invS = 1.f / S;
    re *= invS; im *= invS;
    float n2 = wave_sum(re * re + im * im);
    float scl = 1.f / (sqrtf(n2) + 1e-9f);
    re *= scl; im *= scl;
    float qp[30];
#pragma unroll
    for (int i = 0; i < 30; ++i) qp[i] = qff[i];
    ansatz_layer(re, im, lane, qp);
#pragma unroll
    for (int q = 0; q < 6; ++q) {
      int m = 1 << (5 - q);
      float pre = __shfl_xor(re, m, 64), pim = __shfl_xor(im, m, 64);
      float vx = re * pre + im * pim;
      float vy = (lane & m) ? (im * pre - re * pim) : (re * pim - im * pre);
      float vz = (lane & m) ? -(re * re + im * im) : (re * re + im * im);
      vx = wave_sum(vx); vy = wave_sum(vy); vz = wave_sum(vz);
      if (lane == 0) { qfeatS[q] = vx; qfeatS[6 + q] = vy; qfeatS[12 + q] = vz; }
    }
  }
  __syncthreads();

  float o = out_b[tid];
#pragma unroll
  for (int k = 0; k < 18; ++k) o = fmaf(qfeatS[k], out_w[k * DD + tid], o);
  float s1 = wave_sum(o);
  if (lane == 0) redS[wv] = s1;
  __syncthreads();
  float mu = (redS[0] + redS[1] + redS[2] + redS[3]) * (1.f / 256.f);
  __syncthreads();
  float dv = o - mu;
  float s2 = wave_sum(dv * dv);
  if (lane == 0) redS[wv] = s2;
  __syncthreads();
  float var = (redS[0] + redS[1] + redS[2] + redS[3]) * (1.f / 256.f);
  __syncthreads();
  float on = dv / sqrtf(var + 1e-5f) * ln_g[tid] + ln_b[tid];
  outS[tid] = on;
  __syncthreads();
  float r = cls_b1[tid];
#pragma unroll 8
  for (int d = 0; d < DD; ++d) r = fmaf(outS[d], cls_w1[(size_t)d * DD + tid], r);
  r = fmaxf(r, 0.f);
  float p0 = wave_sum(r * cls_w2[tid * 2 + 0]);
  float p1 = wave_sum(r * cls_w2[tid * 2 + 1]);
  if (lane == 0) redS[wv] = p0;
  __syncthreads();
  float l0 = redS[0] + redS[1] + redS[2] + redS[3];
  __syncthreads();
  if (lane == 0) redS[wv] = p1;
  __syncthreads();
  float l1 = redS[0] + redS[1] + redS[2] + redS[3];
  if (tid == 0) {
    outp[b * 2 + 0] = l0 + cls_b2[0];
    outp[b * 2 + 1] = l1 + cls_b2[1];
  }
}

extern "C" void kernel_launch(void* const* d_in, const int* in_sizes, int n_in,
                              void* d_out, int out_size, void* d_ws, size_t ws_size,
                              hipStream_t stream) {
  const float* x      = (const float*)d_in[0];
  const float* emb_w  = (const float*)d_in[1];
  const float* emb_b  = (const float*)d_in[2];
  const float* att_w1 = (const float*)d_in[3];
  const float* att_b1 = (const float*)d_in[4];
  const float* att_w2 = (const float*)d_in[5];
  // d_in[6] att_b2: unused (softmax shift-invariant)
  const float* proj_w = (const float*)d_in[7];
  const float* proj_b = (const float*)d_in[8];
  const float* mix_re = (const float*)d_in[9];
  const float* mix_im = (const float*)d_in[10];
  const float* qff    = (const float*)d_in[11];
  const float* out_w  = (const float*)d_in[12];
  const float* out_b  = (const float*)d_in[13];
  const float* ln_g   = (const float*)d_in[14];
  const float* ln_b   = (const float*)d_in[15];
  const float* cls_w1 = (const float*)d_in[16];
  const float* cls_b1 = (const float*)d_in[17];
  const float* cls_w2 = (const float*)d_in[18];
  const float* cls_b2 = (const float*)d_in[19];

  char* ws = (char*)d_ws;
  float*  params  = (float*)ws;                      // 16384*60*4 = 3,932,160
  float2* evolved = (float2*)(ws + 3932160);         // 16384*64*8 = 8,388,608
  size_t off = 3932160 + 8388608;
  __bf16* embH   = (__bf16*)(ws + off); off += 32768;
  __bf16* embL   = (__bf16*)(ws + off); off += 32768;
  __bf16* attH   = (__bf16*)(ws + off); off += 65536;
  __bf16* attL   = (__bf16*)(ws + off); off += 65536;
  __bf16* projTH = (__bf16*)(ws + off); off += 32768;
  __bf16* projTL = (__bf16*)(ws + off); off += 32768;  // ~12.58 MB total

  k0_prep<<<256, 256, 0, stream>>>(emb_w, att_w1, proj_w,
                                   embH, embL, attH, attL, projTH, projTL);
  k1_feats_attn_proj<<<BB * 64, 256, 0, stream>>>(
      x, emb_b, att_b1, att_w2, proj_b,
      embH, embL, attH, attL, projTH, projTL, params);
  k2_ansatz<<<BB * NCH * QDIM / 256, 256, 0, stream>>>(params, evolved);
  k3_head<<<BB, 256, 0, stream>>>(evolved, mix_re, mix_im, qff, out_w, out_b,
                                  ln_g, ln_b, cls_w1, cls_b1, cls_w2, cls_b2,
                                  (float*)d_out);
}